// Round 1
// baseline (275.634 us; speedup 1.0000x reference)
//
#include <hip/hip_runtime.h>
#include <cstdint>
#include <cstddef>

#define NEG_FILL -1000000.0f

__device__ __forceinline__ float wave_sum(float v) {
    #pragma unroll
    for (int off = 32; off > 0; off >>= 1) v += __shfl_down(v, off, 64);
    return v;
}
__device__ __forceinline__ float wave_max(float v) {
    #pragma unroll
    for (int off = 32; off > 0; off >>= 1) v = fmaxf(v, __shfl_down(v, off, 64));
    return v;
}

// block reductions over 256 threads (4 waves); leading sync protects s_red reuse
__device__ __forceinline__ float block_sum(float v, float* s_red) {
    v = wave_sum(v);
    __syncthreads();
    if ((threadIdx.x & 63) == 0) s_red[threadIdx.x >> 6] = v;
    __syncthreads();
    return (s_red[0] + s_red[1]) + (s_red[2] + s_red[3]);
}
__device__ __forceinline__ float block_max(float v, float* s_red) {
    v = wave_max(v);
    __syncthreads();
    if ((threadIdx.x & 63) == 0) s_red[threadIdx.x >> 6] = v;
    __syncthreads();
    return fmaxf(fmaxf(s_red[0], s_red[1]), fmaxf(s_red[2], s_red[3]));
}

__global__ void zero_acc(double* acc) {
    if (threadIdx.x < 3) acc[threadIdx.x] = 0.0;
}

// One block per batch row. N = 4096 cells/row, 256 threads x 16 cells.
__global__ __launch_bounds__(256) void criterion_row_kernel(
    const float* __restrict__ pred_legal,
    const float* __restrict__ pred_quality,
    const float* __restrict__ target_legal,
    const float* __restrict__ target_quality,
    double* __restrict__ acc, int Q) {
    const int b = blockIdx.x;
    const int tid = threadIdx.x;

    __shared__ float lined[256];
    __shared__ float matchv[256];
    __shared__ int scan[256];
    __shared__ float s_red[4];

    lined[tid]  = NEG_FILL;
    matchv[tid] = 0.0f;

    const float* __restrict__ xrow = pred_legal   + (size_t)b * 4096;
    const float* __restrict__ trow = target_legal + (size_t)b * 4096;
    const int base = tid * 16;

    float bce = 0.0f;
    unsigned tmask = 0u, pmask = 0u;
    #pragma unroll
    for (int k = 0; k < 4; ++k) {
        float4 x4 = *(const float4*)(xrow + base + k * 4);
        float4 t4 = *(const float4*)(trow + base + k * 4);
        float xs[4] = {x4.x, x4.y, x4.z, x4.w};
        float ts[4] = {t4.x, t4.y, t4.z, t4.w};
        #pragma unroll
        for (int j = 0; j < 4; ++j) {
            float x = xs[j], t = ts[j];
            float w = (t == 0.0f) ? 0.25f : 1.0f;
            bce += w * (fmaxf(x, 0.0f) - x * t + log1pf(expf(-fabsf(x))));
            unsigned bit = 1u << (k * 4 + j);
            if (t == 1.0f) tmask |= bit;
            if (x > 0.0f)  pmask |= bit;
        }
    }
    const int ct = __popc(tmask), cp = __popc(pmask);

    // packed inclusive scan: high 16 bits = t counts, low 16 = p counts
    scan[tid] = (ct << 16) | cp;
    __syncthreads();
    #pragma unroll
    for (int off = 1; off < 256; off <<= 1) {
        int add = (tid >= off) ? scan[tid - off] : 0;
        __syncthreads();
        scan[tid] += add;
        __syncthreads();
    }
    const int incl  = scan[tid];
    const int t_off = (incl >> 16) - ct;
    const int p_off = (incl & 0xFFFF) - cp;

    // scatter: for each cell where both target==1 and pred>0
    const float* __restrict__ pqrow = pred_quality + (size_t)b * Q;
    unsigned both = tmask & pmask;
    while (both) {
        int j = __ffs(both) - 1;
        both &= both - 1;
        unsigned below = (1u << j) - 1u;
        int tr = t_off + __popc(tmask & below);
        int pr = p_off + __popc(pmask & below);
        if (pr < Q - 1 && tr < Q) {
            lined[tr]  = pqrow[pr];
            matchv[tr] = 1.0f;
        }
    }
    __syncthreads();

    // per-row CE over classes [0, Q-1)
    const float v   = (tid < Q - 1) ? lined[tid] : -3.4e38f;
    const float tqv = (tid < Q - 1)
        ? target_quality[(size_t)b * Q + tid] * matchv[tid] : 0.0f;

    const float m  = block_max(v, s_red);
    const float e  = (tid < Q - 1) ? expf(v - m) : 0.0f;
    const float se = block_sum(e, s_red);
    const float lse = m + logf(se);
    const float tsum = block_sum(tqv, s_red);
    const float contrib = (tid < Q - 1)
        ? -(tqv / (tsum + 1e-10f)) * (v - lse) : 0.0f;
    const float csum = block_sum(contrib, s_red);
    const float brow = block_sum(bce, s_red);

    if (tid == 0) {
        atomicAdd(acc + 0, (double)brow);
        atomicAdd(acc + 1, (double)csum);
    }
    if (tid == Q - 1) {
        float pl = pqrow[Q - 1];
        float tl = target_quality[(size_t)b * Q + (Q - 1)];
        float d = pl - tl;
        atomicAdd(acc + 2, (double)(d * d));
    }
}

__global__ void finalize_kernel(const double* __restrict__ acc,
                                float* __restrict__ out, int B, int Q) {
    if (threadIdx.x == 0) {
        out[0] = (float)(acc[0] / ((double)B * 4096.0));
        out[1] = (float)(200.0 * (acc[1] / (double)(Q - 1)) + acc[2] / (double)B);
    }
}

extern "C" void kernel_launch(void* const* d_in, const int* in_sizes, int n_in,
                              void* d_out, int out_size, void* d_ws, size_t ws_size,
                              hipStream_t stream) {
    const float* pred_legal     = (const float*)d_in[0];
    const float* pred_quality   = (const float*)d_in[1];
    const float* target_legal   = (const float*)d_in[2];
    const float* target_quality = (const float*)d_in[3];

    const int B = in_sizes[0] / 4096;       // 4096
    const int Q = in_sizes[1] / B;          // 256

    double* acc = (double*)d_ws;

    zero_acc<<<1, 64, 0, stream>>>(acc);
    criterion_row_kernel<<<B, 256, 0, stream>>>(
        pred_legal, pred_quality, target_legal, target_quality, acc, Q);
    finalize_kernel<<<1, 64, 0, stream>>>(acc, (float*)d_out, B, Q);
}

// Round 2
// 165.856 us; speedup vs baseline: 1.6619x; 1.6619x over previous
//
#include <hip/hip_runtime.h>
#include <cstdint>
#include <cstddef>

#define NEG_FILL -1000000.0f

// One WAVE per batch row; 4 rows per 256-thread block. All rank logic is
// ballot/popcount based (zero barriers in the hot path); ranks are exact
// row-major ranks because segments are processed in row-major order and the
// (t_base, p_base) prefixes are wave-uniform scalar accumulators.
__global__ __launch_bounds__(256) void criterion_rows(
    const float* __restrict__ pred_legal,
    const float* __restrict__ pred_quality,
    const float* __restrict__ target_legal,
    const float* __restrict__ target_quality,
    float* __restrict__ partials, int B) {

    __shared__ float lined[4][256];
    __shared__ float matchv[4][256];

    const int tid = threadIdx.x;
    const int lane = tid & 63;
    const int slot = tid >> 6;
    const int row_raw = blockIdx.x * 4 + slot;
    const bool active = row_raw < B;
    const int row = active ? row_raw : (B - 1);

    #pragma unroll
    for (int k = 0; k < 4; ++k) {
        lined[slot][k * 64 + lane] = NEG_FILL;
        matchv[slot][k * 64 + lane] = 0.0f;
    }

    const float* __restrict__ xrow  = pred_legal     + (size_t)row * 4096;
    const float* __restrict__ trow  = target_legal   + (size_t)row * 4096;
    const float* __restrict__ pqrow = pred_quality   + (size_t)row * 256;
    const float* __restrict__ tqrow = target_quality + (size_t)row * 256;

    float bce = 0.0f;
    int t_base = 0, p_base = 0;
    const uint64_t lm = (1ull << lane) - 1ull;   // lanes strictly below

    // 16 segments of 256 cells; lane i owns cells [i*4, i*4+4) of each segment
    // -> float4 loads are perfectly coalesced (1 KiB per wave instruction).
    #pragma unroll 4
    for (int seg = 0; seg < 16; ++seg) {
        const float4 x4 = *(const float4*)(xrow + seg * 256 + lane * 4);
        const float4 t4 = *(const float4*)(trow + seg * 256 + lane * 4);
        const float xs[4] = {x4.x, x4.y, x4.z, x4.w};
        const float ts[4] = {t4.x, t4.y, t4.z, t4.w};
        uint64_t bt[4], bp[4];
        #pragma unroll
        for (int e = 0; e < 4; ++e) {
            const float x = xs[e], t = ts[e];
            // w*BCE: t==1 -> softplus(-x); t==0 -> 0.25*softplus(x)
            const float L = __logf(1.0f + __expf(-fabsf(x)));
            bce += (t == 1.0f) ? (fmaxf(-x, 0.0f) + L)
                               : 0.25f * (fmaxf(x, 0.0f) + L);
            bt[e] = __ballot(t == 1.0f);
            bp[e] = __ballot(x > 0.0f);
        }
        // scatter matched cells (rare: ~0.2 per row on this data)
        #pragma unroll
        for (int e = 0; e < 4; ++e) {
            if ((ts[e] == 1.0f) && (xs[e] > 0.0f)) {
                int rt = __popcll(bt[0] & lm) + __popcll(bt[1] & lm)
                       + __popcll(bt[2] & lm) + __popcll(bt[3] & lm);
                int rp = __popcll(bp[0] & lm) + __popcll(bp[1] & lm)
                       + __popcll(bp[2] & lm) + __popcll(bp[3] & lm);
                #pragma unroll
                for (int e2 = 0; e2 < 4; ++e2) {
                    if (e2 < e) {
                        rt += (int)((bt[e2] >> lane) & 1ull);
                        rp += (int)((bp[e2] >> lane) & 1ull);
                    }
                }
                const int tr = t_base + rt;
                const int pr = p_base + rp;
                if (pr < 255 && tr < 256) {
                    lined[slot][tr]  = pqrow[pr];
                    matchv[slot][tr] = 1.0f;
                }
            }
        }
        t_base += __popcll(bt[0]) + __popcll(bt[1]) + __popcll(bt[2]) + __popcll(bt[3]);
        p_base += __popcll(bp[0]) + __popcll(bp[1]) + __popcll(bp[2]) + __popcll(bp[3]);
    }

    // single barrier: guarantees LDS scatter visibility (also covers the
    // compiler's aliasing analysis); waves own disjoint LDS slots.
    __syncthreads();

    // ---- per-row CE over classes [0, 255) + MSE on class 255 ----
    float m = -3.0e38f;
    float vs[4], tqs[4];
    #pragma unroll
    for (int k = 0; k < 4; ++k) {
        const int c = k * 64 + lane;
        float v  = lined[slot][c];
        float tq = tqrow[c] * matchv[slot][c];
        if (c < 255) m = fmaxf(m, v);
        else { v = 0.0f; tq = 0.0f; }
        vs[k] = v; tqs[k] = tq;
    }
    #pragma unroll
    for (int off = 32; off > 0; off >>= 1)
        m = fmaxf(m, __shfl_xor(m, off, 64));

    float se = 0.0f, tsum = 0.0f, tv = 0.0f;
    #pragma unroll
    for (int k = 0; k < 4; ++k) {
        const int c = k * 64 + lane;
        if (c < 255) {
            se   += __expf(vs[k] - m);
            tsum += tqs[k];
            tv   += tqs[k] * vs[k];
        }
    }
    float s0 = bce, s1 = se, s2 = tsum, s3 = tv;
    #pragma unroll
    for (int off = 32; off > 0; off >>= 1) {
        s0 += __shfl_xor(s0, off, 64);
        s1 += __shfl_xor(s1, off, 64);
        s2 += __shfl_xor(s2, off, 64);
        s3 += __shfl_xor(s3, off, 64);
    }

    if (active && lane == 0) {
        const float lse  = m + __logf(s1);
        // sum_c -(tq_c/(tsum+eps))*(v_c - lse) = -(tv - lse*tsum)/(tsum+eps)
        const float csum = -(s3 - lse * s2) / (s2 + 1e-10f);
        const float d    = pqrow[255] - tqrow[255];
        float4 o;
        o.x = s0;        // row BCE sum
        o.y = csum;      // row CE contribution
        o.z = d * d;     // row MSE contribution
        o.w = 0.0f;
        *(float4*)(partials + (size_t)row_raw * 4) = o;
    }
}

__global__ __launch_bounds__(256) void finalize_kernel(
    const float* __restrict__ partials, float* __restrict__ out, int B) {
    const int tid = threadIdx.x;
    double s0 = 0.0, s1 = 0.0, s2 = 0.0;
    for (int r = tid; r < B; r += 256) {
        const float4 p = *(const float4*)(partials + (size_t)r * 4);
        s0 += (double)p.x; s1 += (double)p.y; s2 += (double)p.z;
    }
    #pragma unroll
    for (int off = 32; off > 0; off >>= 1) {
        s0 += __shfl_xor(s0, off, 64);
        s1 += __shfl_xor(s1, off, 64);
        s2 += __shfl_xor(s2, off, 64);
    }
    __shared__ double red[3][4];
    const int lane = tid & 63, w = tid >> 6;
    if (lane == 0) { red[0][w] = s0; red[1][w] = s1; red[2][w] = s2; }
    __syncthreads();
    if (tid == 0) {
        const double b = red[0][0] + red[0][1] + red[0][2] + red[0][3];
        const double c = red[1][0] + red[1][1] + red[1][2] + red[1][3];
        const double q = red[2][0] + red[2][1] + red[2][2] + red[2][3];
        out[0] = (float)(b / ((double)B * 4096.0));
        out[1] = (float)(200.0 * (c / 255.0) + q / (double)B);
    }
}

extern "C" void kernel_launch(void* const* d_in, const int* in_sizes, int n_in,
                              void* d_out, int out_size, void* d_ws, size_t ws_size,
                              hipStream_t stream) {
    const float* pred_legal     = (const float*)d_in[0];
    const float* pred_quality   = (const float*)d_in[1];
    const float* target_legal   = (const float*)d_in[2];
    const float* target_quality = (const float*)d_in[3];

    const int B = in_sizes[0] / 4096;   // 4096

    float* partials = (float*)d_ws;     // B * 4 floats

    const int grid = (B + 3) / 4;
    criterion_rows<<<grid, 256, 0, stream>>>(
        pred_legal, pred_quality, target_legal, target_quality, partials, B);
    finalize_kernel<<<1, 256, 0, stream>>>(partials, (float*)d_out, B);
}

// Round 4
// 159.766 us; speedup vs baseline: 1.7252x; 1.0381x over previous
//
#include <hip/hip_runtime.h>
#include <cstdint>
#include <cstddef>

#define NEG_FILL -1000000.0f
#define MAXE 1024

// One BLOCK (4 waves) per batch row. Wave w owns cells [w*1024, (w+1)*1024).
// Ranks within a wave use the R2-proven row-major ballot scheme: per segment,
// gather 4 ballots (one per element slot), then rank(cell lane,e) =
//   popc(all ballots & lanes<me) + own bits at e'<e + running seg base.
// Cross-wave: per-wave totals exchanged once; global rank = prior-wave sum +
// local rank. Matched cells (rare) go through a small LDS entry buffer.
__global__ __launch_bounds__(256) void criterion_rows(
    const float* __restrict__ pred_legal,
    const float* __restrict__ pred_quality,
    const float* __restrict__ target_legal,
    const float* __restrict__ target_quality,
    float* __restrict__ partials, int B) {

    const int b = blockIdx.x;
    const int tid = threadIdx.x;
    const int lane = tid & 63;
    const int w = tid >> 6;

    __shared__ float lined[256];
    __shared__ float matchv[256];
    __shared__ int   cnt_t[4], cnt_p[4];
    __shared__ int   nent;
    __shared__ int   entries[MAXE];
    __shared__ float red4[4][4];
    __shared__ float redm[4];

    lined[tid]  = NEG_FILL;
    matchv[tid] = 0.0f;
    if (tid == 0) nent = 0;
    __syncthreads();

    const float* __restrict__ xrow  = pred_legal     + (size_t)b * 4096;
    const float* __restrict__ trow  = target_legal   + (size_t)b * 4096;
    const float* __restrict__ pqrow = pred_quality   + (size_t)b * 256;
    const float* __restrict__ tqrow = target_quality + (size_t)b * 256;

    const uint64_t lm = (1ull << lane) - 1ull;   // lanes strictly below

    float bce = 0.0f;
    int t_run = 0, p_run = 0;                    // wave-local running counts
    #pragma unroll
    for (int seg = 0; seg < 4; ++seg) {
        const int cbase = w * 1024 + seg * 256 + lane * 4;
        const float4 x4 = *(const float4*)(xrow + cbase);
        const float4 t4 = *(const float4*)(trow + cbase);
        const float xs[4] = {x4.x, x4.y, x4.z, x4.w};
        const float ts[4] = {t4.x, t4.y, t4.z, t4.w};
        uint64_t bt[4], bp[4];
        #pragma unroll
        for (int e = 0; e < 4; ++e) {
            const float x = xs[e], t = ts[e];
            const float L = __logf(1.0f + __expf(-fabsf(x)));
            bce += (t == 1.0f) ? (fmaxf(-x, 0.0f) + L)
                               : 0.25f * (fmaxf(x, 0.0f) + L);
            bt[e] = __ballot(t == 1.0f);
            bp[e] = __ballot(x > 0.0f);
        }
        // row-major local ranks for matched cells (lane-major, then e)
        #pragma unroll
        for (int e = 0; e < 4; ++e) {
            if ((ts[e] == 1.0f) && (xs[e] > 0.0f)) {
                int ltr = t_run + __popcll(bt[0] & lm) + __popcll(bt[1] & lm)
                        + __popcll(bt[2] & lm) + __popcll(bt[3] & lm);
                int lpr = p_run + __popcll(bp[0] & lm) + __popcll(bp[1] & lm)
                        + __popcll(bp[2] & lm) + __popcll(bp[3] & lm);
                #pragma unroll
                for (int e2 = 0; e2 < 4; ++e2) {
                    if (e2 < e) {
                        ltr += (int)((bt[e2] >> lane) & 1ull);
                        lpr += (int)((bp[e2] >> lane) & 1ull);
                    }
                }
                // local filter: global rank >= local rank, so these can't win
                if (ltr < 256 && lpr < 255) {
                    const int idx = atomicAdd(&nent, 1);
                    if (idx < MAXE)
                        entries[idx] = (w << 16) | (ltr << 8) | lpr;
                }
            }
        }
        t_run += (int)(__popcll(bt[0]) + __popcll(bt[1])
                     + __popcll(bt[2]) + __popcll(bt[3]));
        p_run += (int)(__popcll(bp[0]) + __popcll(bp[1])
                     + __popcll(bp[2]) + __popcll(bp[3]));
    }
    if (lane == 0) { cnt_t[w] = t_run; cnt_p[w] = p_run; }
    __syncthreads();

    // scatter: globalize ranks (t-ranks are unique -> no write conflicts)
    int ne = nent; if (ne > MAXE) ne = MAXE;
    for (int i = tid; i < ne; i += 256) {
        const int ent = entries[i];
        const int ew = ent >> 16, ltr = (ent >> 8) & 0xFF, lpr = ent & 0xFF;
        int bt0 = 0, bp0 = 0;
        #pragma unroll
        for (int k = 0; k < 4; ++k) {
            if (k < ew) { bt0 += cnt_t[k]; bp0 += cnt_p[k]; }
        }
        const int tr = bt0 + ltr, pr = bp0 + lpr;
        if (tr < 256 && pr < 255) {
            lined[tr]  = pqrow[pr];
            matchv[tr] = 1.0f;
        }
    }
    __syncthreads();

    // ---- CE over classes [0,255): thread c <-> class c ----
    const int c = tid;
    const float v  = (c < 255) ? lined[c] : -3.0e38f;
    const float tq = (c < 255) ? tqrow[c] * matchv[c] : 0.0f;

    float m = v;
    #pragma unroll
    for (int off = 32; off > 0; off >>= 1)
        m = fmaxf(m, __shfl_xor(m, off, 64));
    if (lane == 0) redm[w] = m;
    __syncthreads();
    m = fmaxf(fmaxf(redm[0], redm[1]), fmaxf(redm[2], redm[3]));

    float s0 = bce;
    float s1 = (c < 255) ? __expf(v - m) : 0.0f;
    float s2 = tq;
    float s3 = (c < 255) ? tq * v : 0.0f;
    #pragma unroll
    for (int off = 32; off > 0; off >>= 1) {
        s0 += __shfl_xor(s0, off, 64);
        s1 += __shfl_xor(s1, off, 64);
        s2 += __shfl_xor(s2, off, 64);
        s3 += __shfl_xor(s3, off, 64);
    }
    if (lane == 0) {
        red4[w][0] = s0; red4[w][1] = s1; red4[w][2] = s2; red4[w][3] = s3;
    }
    __syncthreads();
    if (tid == 0) {
        float S0 = 0, S1 = 0, S2 = 0, S3 = 0;
        #pragma unroll
        for (int k = 0; k < 4; ++k) {
            S0 += red4[k][0]; S1 += red4[k][1];
            S2 += red4[k][2]; S3 += red4[k][3];
        }
        const float lse  = m + __logf(S1);
        // sum_c -(tq_c/(tsum+eps))*(v_c - lse) = -(tv - lse*tsum)/(tsum+eps)
        const float csum = -(S3 - lse * S2) / (S2 + 1e-10f);
        const float d    = pqrow[255] - tqrow[255];
        float4 o;
        o.x = S0; o.y = csum; o.z = d * d; o.w = 0.0f;
        *(float4*)(partials + (size_t)b * 4) = o;
    }
}

__global__ __launch_bounds__(256) void finalize_kernel(
    const float* __restrict__ partials, float* __restrict__ out, int B) {
    const int tid = threadIdx.x;
    double s0 = 0.0, s1 = 0.0, s2 = 0.0;
    for (int r = tid; r < B; r += 256) {
        const float4 p = *(const float4*)(partials + (size_t)r * 4);
        s0 += (double)p.x; s1 += (double)p.y; s2 += (double)p.z;
    }
    #pragma unroll
    for (int off = 32; off > 0; off >>= 1) {
        s0 += __shfl_xor(s0, off, 64);
        s1 += __shfl_xor(s1, off, 64);
        s2 += __shfl_xor(s2, off, 64);
    }
    __shared__ double red[3][4];
    const int lane = tid & 63, w = tid >> 6;
    if (lane == 0) { red[0][w] = s0; red[1][w] = s1; red[2][w] = s2; }
    __syncthreads();
    if (tid == 0) {
        const double bs = red[0][0] + red[0][1] + red[0][2] + red[0][3];
        const double cs = red[1][0] + red[1][1] + red[1][2] + red[1][3];
        const double qs = red[2][0] + red[2][1] + red[2][2] + red[2][3];
        out[0] = (float)(bs / ((double)B * 4096.0));
        out[1] = (float)(200.0 * (cs / 255.0) + qs / (double)B);
    }
}

extern "C" void kernel_launch(void* const* d_in, const int* in_sizes, int n_in,
                              void* d_out, int out_size, void* d_ws, size_t ws_size,
                              hipStream_t stream) {
    const float* pred_legal     = (const float*)d_in[0];
    const float* pred_quality   = (const float*)d_in[1];
    const float* target_legal   = (const float*)d_in[2];
    const float* target_quality = (const float*)d_in[3];

    const int B = in_sizes[0] / 4096;   // 4096

    float* partials = (float*)d_ws;     // B * 4 floats

    criterion_rows<<<B, 256, 0, stream>>>(
        pred_legal, pred_quality, target_legal, target_quality, partials, B);
    finalize_kernel<<<1, 256, 0, stream>>>(partials, (float*)d_out, B);
}